// Round 2
// baseline (297.486 us; speedup 1.0000x reference)
//
#include <hip/hip_runtime.h>
#include <hip/hip_bf16.h>

typedef _Float16 f16;
typedef __attribute__((ext_vector_type(8))) f16 h8;
typedef __attribute__((ext_vector_type(4))) float f32x4;
typedef __attribute__((ext_vector_type(8))) short short8;

static __device__ __forceinline__ short h2s(f16 h) { return __builtin_bit_cast(short, h); }

#define BM 128
#define BKD 32
#define LDK 40  // 32 + 8 shorts pad; row stride 80 B

// C = A[M][K] @ W[N][K]^T + bias.
// AMODE: 0 = A fp32 global, 1 = A fp16 (short) global.
// SPLIT: 1 = hi/lo split staging of A and B, 3-term MFMA (fp32-accurate).
// EPI:   0 = fp32 out [M][1024]; 1 = fp16 hi/lo to o0/o1 [B,H,S,64]; 2 = fp16 to o0 [B,H,S,64].
template <int AMODE, int SPLIT, int EPI>
static __device__ __forceinline__ void gemm_body(const void* __restrict__ Av,
                                                 const float* __restrict__ W,
                                                 const float* __restrict__ bias,
                                                 short* __restrict__ o0,
                                                 short* __restrict__ o1,
                                                 float* __restrict__ of) {
    __shared__ __align__(16) short smem[(SPLIT ? 4 : 2) * BM * LDK];
    short* Ah = smem;
    short* Al = smem + BM * LDK;                    // used only if SPLIT
    short* Bh = smem + (SPLIT ? 2 : 1) * BM * LDK;
    short* Bl = smem + 3 * BM * LDK;                // used only if SPLIT

    const int K = 1024;
    const int tid = threadIdx.x;
    const int lane = tid & 63;
    const int w = tid >> 6;
    const int lr = lane & 15, lg = lane >> 4;
    const int wm = (w & 1) * 64, wn = (w >> 1) * 64;
    const int m0 = blockIdx.x * BM, n0 = blockIdx.y * BM;

    const int sr = tid >> 1;        // staged row 0..127
    const int sc = (tid & 1) * 16;  // staged col 0 or 16

    f32x4 acc[4][4] = {};

    float a_f[16];
    float b_f[16];
    short8 a_h8[2];

    // prologue: load tile t=0 into regs
    {
        const float* Bp = W + (size_t)(n0 + sr) * K + sc;
#pragma unroll
        for (int i = 0; i < 4; i++) {
            float4 t = *(const float4*)(Bp + 4 * i);
            b_f[4 * i] = t.x; b_f[4 * i + 1] = t.y; b_f[4 * i + 2] = t.z; b_f[4 * i + 3] = t.w;
        }
        if (AMODE == 1) {
            const short* Ap = (const short*)Av + (size_t)(m0 + sr) * K + sc;
            a_h8[0] = *(const short8*)(Ap);
            a_h8[1] = *(const short8*)(Ap + 8);
        } else {
            const float* Ap = (const float*)Av + (size_t)(m0 + sr) * K + sc;
#pragma unroll
            for (int i = 0; i < 4; i++) {
                float4 t = *(const float4*)(Ap + 4 * i);
                a_f[4 * i] = t.x; a_f[4 * i + 1] = t.y; a_f[4 * i + 2] = t.z; a_f[4 * i + 3] = t.w;
            }
        }
    }

    const int NT = K / BKD;  // 32
    for (int t = 0; t < NT; ++t) {
        // stage current regs -> LDS (convert fp32 -> fp16 hi[/lo])
        {
            short8 bh0, bh1, bl0, bl1;
#pragma unroll
            for (int j = 0; j < 8; ++j) {
                f16 h0 = (f16)b_f[j];
                f16 h1 = (f16)b_f[8 + j];
                bh0[j] = h2s(h0);
                bh1[j] = h2s(h1);
                if (SPLIT) {
                    bl0[j] = h2s((f16)(b_f[j] - (float)h0));
                    bl1[j] = h2s((f16)(b_f[8 + j] - (float)h1));
                }
            }
            *(short8*)&Bh[sr * LDK + sc] = bh0;
            *(short8*)&Bh[sr * LDK + sc + 8] = bh1;
            if (SPLIT) {
                *(short8*)&Bl[sr * LDK + sc] = bl0;
                *(short8*)&Bl[sr * LDK + sc + 8] = bl1;
            }
            if (AMODE == 1) {
                *(short8*)&Ah[sr * LDK + sc] = a_h8[0];
                *(short8*)&Ah[sr * LDK + sc + 8] = a_h8[1];
            } else {
                short8 ah0, ah1, al0, al1;
#pragma unroll
                for (int j = 0; j < 8; ++j) {
                    f16 h0 = (f16)a_f[j];
                    f16 h1 = (f16)a_f[8 + j];
                    ah0[j] = h2s(h0);
                    ah1[j] = h2s(h1);
                    if (SPLIT) {
                        al0[j] = h2s((f16)(a_f[j] - (float)h0));
                        al1[j] = h2s((f16)(a_f[8 + j] - (float)h1));
                    }
                }
                *(short8*)&Ah[sr * LDK + sc] = ah0;
                *(short8*)&Ah[sr * LDK + sc + 8] = ah1;
                if (SPLIT) {
                    *(short8*)&Al[sr * LDK + sc] = al0;
                    *(short8*)&Al[sr * LDK + sc + 8] = al1;
                }
            }
        }
        __syncthreads();
        // prefetch next tile into regs
        if (t + 1 < NT) {
            const int ko = (t + 1) * BKD;
            const float* Bp = W + (size_t)(n0 + sr) * K + ko + sc;
#pragma unroll
            for (int i = 0; i < 4; i++) {
                float4 tv = *(const float4*)(Bp + 4 * i);
                b_f[4 * i] = tv.x; b_f[4 * i + 1] = tv.y; b_f[4 * i + 2] = tv.z; b_f[4 * i + 3] = tv.w;
            }
            if (AMODE == 1) {
                const short* Ap = (const short*)Av + (size_t)(m0 + sr) * K + ko + sc;
                a_h8[0] = *(const short8*)(Ap);
                a_h8[1] = *(const short8*)(Ap + 8);
            } else {
                const float* Ap = (const float*)Av + (size_t)(m0 + sr) * K + ko + sc;
#pragma unroll
                for (int i = 0; i < 4; i++) {
                    float4 tv = *(const float4*)(Ap + 4 * i);
                    a_f[4 * i] = tv.x; a_f[4 * i + 1] = tv.y; a_f[4 * i + 2] = tv.z; a_f[4 * i + 3] = tv.w;
                }
            }
        }
        // compute current tile from LDS
        {
            h8 afh[4], bfh[4], afl[4], bfl[4];
#pragma unroll
            for (int f = 0; f < 4; ++f) {
                afh[f] = *(const h8*)&Ah[(wm + f * 16 + lr) * LDK + lg * 8];
                bfh[f] = *(const h8*)&Bh[(wn + f * 16 + lr) * LDK + lg * 8];
                if (SPLIT) {
                    afl[f] = *(const h8*)&Al[(wm + f * 16 + lr) * LDK + lg * 8];
                    bfl[f] = *(const h8*)&Bl[(wn + f * 16 + lr) * LDK + lg * 8];
                }
            }
#pragma unroll
            for (int i = 0; i < 4; i++)
#pragma unroll
                for (int j = 0; j < 4; j++) {
                    acc[i][j] = __builtin_amdgcn_mfma_f32_16x16x32_f16(afh[i], bfh[j], acc[i][j], 0, 0, 0);
                    if (SPLIT) {
                        acc[i][j] = __builtin_amdgcn_mfma_f32_16x16x32_f16(afl[i], bfh[j], acc[i][j], 0, 0, 0);
                        acc[i][j] = __builtin_amdgcn_mfma_f32_16x16x32_f16(afh[i], bfl[j], acc[i][j], 0, 0, 0);
                    }
                }
        }
        __syncthreads();
    }

    // epilogue. C-frag: row=(lane>>4)*4+i, col=lane&15
#pragma unroll
    for (int fn = 0; fn < 4; ++fn) {
        const int n = n0 + wn + fn * 16 + lr;
        const float bia = bias[n];
#pragma unroll
        for (int fm = 0; fm < 4; ++fm) {
#pragma unroll
            for (int i = 0; i < 4; i++) {
                const int m = m0 + wm + fm * 16 + lg * 4 + i;
                const float val = acc[fm][fn][i] + bia;
                if (EPI == 0) {
                    of[(size_t)m * 1024 + n] = val;
                } else {
                    const int bb = m >> 11, s = m & 2047, hh = n >> 6, d = n & 63;
                    const size_t off = (((size_t)(bb * 16 + hh) * 2048 + s) << 6) + d;
                    if (EPI == 1) {
                        f16 vh = (f16)val;
                        f16 vl = (f16)(val - (float)vh);
                        o0[off] = h2s(vh);
                        o1[off] = h2s(vl);
                    } else {
                        o0[off] = h2s((f16)val);
                    }
                }
            }
        }
    }
}

__global__ __launch_bounds__(256) void qk_proj_kernel(
    const float* __restrict__ q, const float* __restrict__ k,
    const float* __restrict__ Wq, const float* __restrict__ Wk,
    const float* __restrict__ bq, const float* __restrict__ bk,
    short* __restrict__ Qh, short* __restrict__ Ql,
    short* __restrict__ Kh, short* __restrict__ Kl) {
    if (blockIdx.z == 0)
        gemm_body<0, 1, 1>(q, Wq, bq, Qh, Ql, nullptr);
    else
        gemm_body<0, 1, 1>(k, Wk, bk, Kh, Kl, nullptr);
}

__global__ __launch_bounds__(256) void v_proj_kernel(const float* __restrict__ v,
                                                     const float* __restrict__ Wv,
                                                     const float* __restrict__ bv,
                                                     short* __restrict__ Vb) {
    gemm_body<0, 0, 2>(v, Wv, bv, Vb, nullptr, nullptr);
}

__global__ __launch_bounds__(256) void oproj_kernel(const short* __restrict__ Xb,
                                                    const float* __restrict__ Wo,
                                                    const float* __restrict__ bo,
                                                    float* __restrict__ out) {
    gemm_body<1, 0, 0>(Xb, Wo, nullptr, nullptr, nullptr, out);
    (void)bo;
}

// same as oproj but with bias pointer used
__global__ __launch_bounds__(256) void oproj_kernel2(const short* __restrict__ Xb,
                                                     const float* __restrict__ Wo,
                                                     const float* __restrict__ bo,
                                                     float* __restrict__ out) {
    gemm_body<1, 0, 0>(Xb, Wo, bo, nullptr, nullptr, out);
}

// Flash attention with threshold mask. Q/K hi+lo fp16, V fp16; all [B*H][S][64].
__global__ __launch_bounds__(256) void attn_kernel(const short* __restrict__ Qh,
                                                   const short* __restrict__ Ql,
                                                   const short* __restrict__ Kh,
                                                   const short* __restrict__ Kl,
                                                   const short* __restrict__ Vb,
                                                   const float* __restrict__ rawthr,
                                                   short* __restrict__ Xb) {
    __shared__ __align__(16) short Ksh[64][72];
    __shared__ __align__(16) short Ksl[64][72];
    __shared__ __align__(16) short Vt[64][72];     // [feat][key]
    __shared__ __align__(16) short Ps[4][32][72];  // per-wave P tile
    const int tid = threadIdx.x, lane = tid & 63, w = tid >> 6;
    const int lr = lane & 15, lg = lane >> 4;
    const int bh = blockIdx.y;
    const int b = bh >> 4, h = bh & 15;
    const size_t base = (size_t)bh * 2048 * 64;
    const float rt = rawthr[h];
    const float thr = rt > 20.f ? rt : log1pf(expf(rt));
    const int qrow = blockIdx.x * 128 + w * 32;

    // Q fragments (hi+lo) in registers: rows qrow..qrow+31, feats 0..63
    h8 qfh[2][2], qfl[2][2];
#pragma unroll
    for (int fm = 0; fm < 2; ++fm)
#pragma unroll
        for (int kk = 0; kk < 2; ++kk) {
            const size_t off = base + (size_t)(qrow + fm * 16 + lr) * 64 + kk * 32 + lg * 8;
            qfh[fm][kk] = *(const h8*)(Qh + off);
            qfl[fm][kk] = *(const h8*)(Ql + off);
        }

    f32x4 acc[2][4] = {};
    float mrun[8], lrun[8];
#pragma unroll
    for (int r = 0; r < 8; ++r) { mrun[r] = -INFINITY; lrun[r] = 0.f; }

    const int skey = tid >> 2;       // 0..63
    const int sfe = (tid & 3) * 16;  // 0,16,32,48
    short8 khreg0, khreg1, klreg0, klreg1, vreg0, vreg1;
    {
        const size_t off = base + (size_t)skey * 64 + sfe;
        khreg0 = *(const short8*)(Kh + off);
        khreg1 = *(const short8*)(Kh + off + 8);
        klreg0 = *(const short8*)(Kl + off);
        klreg1 = *(const short8*)(Kl + off + 8);
        vreg0 = *(const short8*)(Vb + off);
        vreg1 = *(const short8*)(Vb + off + 8);
    }

    for (int kt = 0; kt < 32; ++kt) {
        __syncthreads();  // previous iteration's LDS reads done
        *(short8*)&Ksh[skey][sfe] = khreg0;
        *(short8*)&Ksh[skey][sfe + 8] = khreg1;
        *(short8*)&Ksl[skey][sfe] = klreg0;
        *(short8*)&Ksl[skey][sfe + 8] = klreg1;
#pragma unroll
        for (int j = 0; j < 8; ++j) {
            Vt[sfe + j][skey] = vreg0[j];
            Vt[sfe + 8 + j][skey] = vreg1[j];
        }
        __syncthreads();
        if (kt + 1 < 32) {  // prefetch next KV tile into regs (overlaps compute)
            const size_t off = base + (size_t)((kt + 1) * 64 + skey) * 64 + sfe;
            khreg0 = *(const short8*)(Kh + off);
            khreg1 = *(const short8*)(Kh + off + 8);
            klreg0 = *(const short8*)(Kl + off);
            klreg1 = *(const short8*)(Kl + off + 8);
            vreg0 = *(const short8*)(Vb + off);
            vreg1 = *(const short8*)(Vb + off + 8);
        }
        // S = Q K^T  (3-term split: accurate to ~1e-5)
        f32x4 sc[2][4] = {};
#pragma unroll
        for (int fn = 0; fn < 4; ++fn) {
#pragma unroll
            for (int kk = 0; kk < 2; ++kk) {
                const h8 khf = *(const h8*)&Ksh[fn * 16 + lr][kk * 32 + lg * 8];
                const h8 klf = *(const h8*)&Ksl[fn * 16 + lr][kk * 32 + lg * 8];
#pragma unroll
                for (int fm = 0; fm < 2; ++fm) {
                    sc[fm][fn] = __builtin_amdgcn_mfma_f32_16x16x32_f16(qfh[fm][kk], khf, sc[fm][fn], 0, 0, 0);
                    sc[fm][fn] = __builtin_amdgcn_mfma_f32_16x16x32_f16(qfl[fm][kk], khf, sc[fm][fn], 0, 0, 0);
                    sc[fm][fn] = __builtin_amdgcn_mfma_f32_16x16x32_f16(qfh[fm][kk], klf, sc[fm][fn], 0, 0, 0);
                }
            }
        }
        // scale, threshold-mask, online softmax
        float corr[8];
#pragma unroll
        for (int fm = 0; fm < 2; ++fm) {
#pragma unroll
            for (int i = 0; i < 4; ++i) {
                const int r = fm * 4 + i;
                float mx = -INFINITY;
#pragma unroll
                for (int fn = 0; fn < 4; ++fn) {
                    float s = sc[fm][fn][i] * 0.125f;
                    s = (s <= thr) ? -1e9f : s;
                    sc[fm][fn][i] = s;
                    mx = fmaxf(mx, s);
                }
                mx = fmaxf(mx, __shfl_xor(mx, 1));
                mx = fmaxf(mx, __shfl_xor(mx, 2));
                mx = fmaxf(mx, __shfl_xor(mx, 4));
                mx = fmaxf(mx, __shfl_xor(mx, 8));
                const float mnew = fmaxf(mrun[r], mx);
                const float c = __expf(mrun[r] - mnew);  // exp(-inf)=0 on first tile
                float sum = 0.f;
#pragma unroll
                for (int fn = 0; fn < 4; ++fn) {
                    const float p = __expf(sc[fm][fn][i] - mnew);
                    sc[fm][fn][i] = p;
                    sum += p;
                }
                sum += __shfl_xor(sum, 1);
                sum += __shfl_xor(sum, 2);
                sum += __shfl_xor(sum, 4);
                sum += __shfl_xor(sum, 8);
                lrun[r] = lrun[r] * c + sum;
                mrun[r] = mnew;
                corr[r] = c;
            }
        }
#pragma unroll
        for (int fm = 0; fm < 2; ++fm)
#pragma unroll
            for (int fv = 0; fv < 4; ++fv)
#pragma unroll
                for (int i = 0; i < 4; ++i) acc[fm][fv][i] *= corr[fm * 4 + i];
        // P -> LDS (C-layout -> A-layout relayout), per-wave buffer, no barrier needed
#pragma unroll
        for (int fm = 0; fm < 2; ++fm)
#pragma unroll
            for (int fn = 0; fn < 4; ++fn)
#pragma unroll
                for (int i = 0; i < 4; ++i)
                    Ps[w][fm * 16 + lg * 4 + i][fn * 16 + lr] = h2s((f16)sc[fm][fn][i]);
        // O += P V
        h8 pa[2][2];
#pragma unroll
        for (int fm = 0; fm < 2; ++fm)
#pragma unroll
            for (int kk = 0; kk < 2; ++kk)
                pa[fm][kk] = *(const h8*)&Ps[w][fm * 16 + lr][kk * 32 + lg * 8];
#pragma unroll
        for (int kk = 0; kk < 2; ++kk) {
#pragma unroll
            for (int fv = 0; fv < 4; ++fv) {
                const h8 vf = *(const h8*)&Vt[fv * 16 + lr][kk * 32 + lg * 8];
#pragma unroll
                for (int fm = 0; fm < 2; ++fm)
                    acc[fm][fv] = __builtin_amdgcn_mfma_f32_16x16x32_f16(pa[fm][kk], vf, acc[fm][fv], 0, 0, 0);
            }
        }
    }
    // epilogue: x = acc / l, store fp16 to [B,S,H*64]
#pragma unroll
    for (int fm = 0; fm < 2; ++fm) {
#pragma unroll
        for (int i = 0; i < 4; ++i) {
            const int r = fm * 4 + i;
            const float inv = 1.f / lrun[r];
            const int s = qrow + fm * 16 + lg * 4 + i;
#pragma unroll
            for (int fv = 0; fv < 4; ++fv) {
                const int d = fv * 16 + lr;
                Xb[((size_t)(b * 2048 + s) << 10) + (h << 6) + d] = h2s((f16)(acc[fm][fv][i] * inv));
            }
        }
    }
}

extern "C" void kernel_launch(void* const* d_in, const int* in_sizes, int n_in,
                              void* d_out, int out_size, void* d_ws, size_t ws_size,
                              hipStream_t stream) {
    const float* q = (const float*)d_in[0];
    const float* k = (const float*)d_in[1];
    const float* v = (const float*)d_in[2];
    const float* Wq = (const float*)d_in[3];
    const float* bq = (const float*)d_in[4];
    const float* Wk = (const float*)d_in[5];
    const float* bk = (const float*)d_in[6];
    const float* Wv = (const float*)d_in[7];
    const float* bv = (const float*)d_in[8];
    const float* Wo = (const float*)d_in[9];
    const float* bo = (const float*)d_in[10];
    const float* thr = (const float*)d_in[11];
    float* out = (float*)d_out;

    const size_t HS = (size_t)2 * 16 * 2048 * 64;  // 4,194,304 elems per tensor
    short* Qh = (short*)d_ws;
    short* Ql = Qh + HS;
    short* Kh = Ql + HS;
    short* Kl = Kh + HS;
    short* Vb = Kl + HS;
    short* Xb = Vb + HS;

    qk_proj_kernel<<<dim3(32, 8, 2), 256, 0, stream>>>(q, k, Wq, Wk, bq, bk, Qh, Ql, Kh, Kl);
    v_proj_kernel<<<dim3(32, 8), 256, 0, stream>>>(v, Wv, bv, Vb);
    attn_kernel<<<dim3(16, 32), 256, 0, stream>>>(Qh, Ql, Kh, Kl, Vb, thr, Xb);
    oproj_kernel2<<<dim3(32, 8), 256, 0, stream>>>(Xb, Wo, bo, out);
}

// Round 3
// 254.418 us; speedup vs baseline: 1.1693x; 1.1693x over previous
//
#include <hip/hip_runtime.h>
#include <hip/hip_bf16.h>

typedef _Float16 f16;
typedef __attribute__((ext_vector_type(8))) f16 h8;
typedef __attribute__((ext_vector_type(4))) float f32x4;
typedef __attribute__((ext_vector_type(8))) short short8;

static __device__ __forceinline__ short h2s(f16 h) { return __builtin_bit_cast(short, h); }

#define BM 128
#define BKD 32
#define LDK 40  // 32 + 8 shorts pad; row stride 80 B

// C = A[M][K] @ W[N][K]^T + bias.
// AMODE: 0 = A fp32 global, 1 = A fp16 (short) global.
// SPLIT: 1 = hi/lo split staging of A and B, 3-term MFMA (fp32-accurate).
// EPI:   0 = fp32 out [M][1024]; 1 = fp16 hi/lo to o0/o1 [B,H,S,64];
//        2 = fp16 to o0 [B,H,S,64]; 3 = fp16 to o0 TRANSPOSED [B,H,64,S].
template <int AMODE, int SPLIT, int EPI>
static __device__ __forceinline__ void gemm_body(const void* __restrict__ Av,
                                                 const float* __restrict__ W,
                                                 const float* __restrict__ bias,
                                                 short* __restrict__ o0,
                                                 short* __restrict__ o1,
                                                 float* __restrict__ of) {
    __shared__ __align__(16) short smem[(SPLIT ? 4 : 2) * BM * LDK];
    short* Ah = smem;
    short* Al = smem + BM * LDK;                    // used only if SPLIT
    short* Bh = smem + (SPLIT ? 2 : 1) * BM * LDK;
    short* Bl = smem + 3 * BM * LDK;                // used only if SPLIT

    const int K = 1024;
    const int tid = threadIdx.x;
    const int lane = tid & 63;
    const int w = tid >> 6;
    const int lr = lane & 15, lg = lane >> 4;
    const int wm = (w & 1) * 64, wn = (w >> 1) * 64;
    const int m0 = blockIdx.x * BM, n0 = blockIdx.y * BM;

    const int sr = tid >> 1;        // staged row 0..127
    const int sc = (tid & 1) * 16;  // staged col 0 or 16

    f32x4 acc[4][4] = {};

    float a_f[16];
    float b_f[16];
    short8 a_h8[2];

    // prologue: load tile t=0 into regs
    {
        const float* Bp = W + (size_t)(n0 + sr) * K + sc;
#pragma unroll
        for (int i = 0; i < 4; i++) {
            float4 t = *(const float4*)(Bp + 4 * i);
            b_f[4 * i] = t.x; b_f[4 * i + 1] = t.y; b_f[4 * i + 2] = t.z; b_f[4 * i + 3] = t.w;
        }
        if (AMODE == 1) {
            const short* Ap = (const short*)Av + (size_t)(m0 + sr) * K + sc;
            a_h8[0] = *(const short8*)(Ap);
            a_h8[1] = *(const short8*)(Ap + 8);
        } else {
            const float* Ap = (const float*)Av + (size_t)(m0 + sr) * K + sc;
#pragma unroll
            for (int i = 0; i < 4; i++) {
                float4 t = *(const float4*)(Ap + 4 * i);
                a_f[4 * i] = t.x; a_f[4 * i + 1] = t.y; a_f[4 * i + 2] = t.z; a_f[4 * i + 3] = t.w;
            }
        }
    }

    const int NT = K / BKD;  // 32
    for (int t = 0; t < NT; ++t) {
        // stage current regs -> LDS (convert fp32 -> fp16 hi[/lo])
        {
            short8 bh0, bh1, bl0, bl1;
#pragma unroll
            for (int j = 0; j < 8; ++j) {
                f16 h0 = (f16)b_f[j];
                f16 h1 = (f16)b_f[8 + j];
                bh0[j] = h2s(h0);
                bh1[j] = h2s(h1);
                if (SPLIT) {
                    bl0[j] = h2s((f16)(b_f[j] - (float)h0));
                    bl1[j] = h2s((f16)(b_f[8 + j] - (float)h1));
                }
            }
            *(short8*)&Bh[sr * LDK + sc] = bh0;
            *(short8*)&Bh[sr * LDK + sc + 8] = bh1;
            if (SPLIT) {
                *(short8*)&Bl[sr * LDK + sc] = bl0;
                *(short8*)&Bl[sr * LDK + sc + 8] = bl1;
            }
            if (AMODE == 1) {
                *(short8*)&Ah[sr * LDK + sc] = a_h8[0];
                *(short8*)&Ah[sr * LDK + sc + 8] = a_h8[1];
            } else {
                short8 ah0, ah1, al0, al1;
#pragma unroll
                for (int j = 0; j < 8; ++j) {
                    f16 h0 = (f16)a_f[j];
                    f16 h1 = (f16)a_f[8 + j];
                    ah0[j] = h2s(h0);
                    ah1[j] = h2s(h1);
                    if (SPLIT) {
                        al0[j] = h2s((f16)(a_f[j] - (float)h0));
                        al1[j] = h2s((f16)(a_f[8 + j] - (float)h1));
                    }
                }
                *(short8*)&Ah[sr * LDK + sc] = ah0;
                *(short8*)&Ah[sr * LDK + sc + 8] = ah1;
                if (SPLIT) {
                    *(short8*)&Al[sr * LDK + sc] = al0;
                    *(short8*)&Al[sr * LDK + sc + 8] = al1;
                }
            }
        }
        __syncthreads();
        // prefetch next tile into regs
        if (t + 1 < NT) {
            const int ko = (t + 1) * BKD;
            const float* Bp = W + (size_t)(n0 + sr) * K + ko + sc;
#pragma unroll
            for (int i = 0; i < 4; i++) {
                float4 tv = *(const float4*)(Bp + 4 * i);
                b_f[4 * i] = tv.x; b_f[4 * i + 1] = tv.y; b_f[4 * i + 2] = tv.z; b_f[4 * i + 3] = tv.w;
            }
            if (AMODE == 1) {
                const short* Ap = (const short*)Av + (size_t)(m0 + sr) * K + ko + sc;
                a_h8[0] = *(const short8*)(Ap);
                a_h8[1] = *(const short8*)(Ap + 8);
            } else {
                const float* Ap = (const float*)Av + (size_t)(m0 + sr) * K + ko + sc;
#pragma unroll
                for (int i = 0; i < 4; i++) {
                    float4 tv = *(const float4*)(Ap + 4 * i);
                    a_f[4 * i] = tv.x; a_f[4 * i + 1] = tv.y; a_f[4 * i + 2] = tv.z; a_f[4 * i + 3] = tv.w;
                }
            }
        }
        // compute current tile from LDS
        {
            h8 afh[4], bfh[4], afl[4], bfl[4];
#pragma unroll
            for (int f = 0; f < 4; ++f) {
                afh[f] = *(const h8*)&Ah[(wm + f * 16 + lr) * LDK + lg * 8];
                bfh[f] = *(const h8*)&Bh[(wn + f * 16 + lr) * LDK + lg * 8];
                if (SPLIT) {
                    afl[f] = *(const h8*)&Al[(wm + f * 16 + lr) * LDK + lg * 8];
                    bfl[f] = *(const h8*)&Bl[(wn + f * 16 + lr) * LDK + lg * 8];
                }
            }
#pragma unroll
            for (int i = 0; i < 4; i++)
#pragma unroll
                for (int j = 0; j < 4; j++) {
                    acc[i][j] = __builtin_amdgcn_mfma_f32_16x16x32_f16(afh[i], bfh[j], acc[i][j], 0, 0, 0);
                    if (SPLIT) {
                        acc[i][j] = __builtin_amdgcn_mfma_f32_16x16x32_f16(afl[i], bfh[j], acc[i][j], 0, 0, 0);
                        acc[i][j] = __builtin_amdgcn_mfma_f32_16x16x32_f16(afh[i], bfl[j], acc[i][j], 0, 0, 0);
                    }
                }
        }
        __syncthreads();
    }

    // epilogue. C-frag: row=(lane>>4)*4+i, col=lane&15
#pragma unroll
    for (int fn = 0; fn < 4; ++fn) {
        const int n = n0 + wn + fn * 16 + lr;
        const float bia = bias[n];
#pragma unroll
        for (int fm = 0; fm < 4; ++fm) {
#pragma unroll
            for (int i = 0; i < 4; i++) {
                const int m = m0 + wm + fm * 16 + lg * 4 + i;
                const float val = acc[fm][fn][i] + bia;
                if (EPI == 0) {
                    of[(size_t)m * 1024 + n] = val;
                } else {
                    const int bb = m >> 11, s = m & 2047, hh = n >> 6, d = n & 63;
                    if (EPI == 1) {
                        const size_t off = (((size_t)(bb * 16 + hh) * 2048 + s) << 6) + d;
                        f16 vh = (f16)val;
                        f16 vl = (f16)(val - (float)vh);
                        o0[off] = h2s(vh);
                        o1[off] = h2s(vl);
                    } else if (EPI == 2) {
                        const size_t off = (((size_t)(bb * 16 + hh) * 2048 + s) << 6) + d;
                        o0[off] = h2s((f16)val);
                    } else {  // EPI == 3: transposed [B,H,64,S]
                        const size_t off = ((size_t)(bb * 16 + hh) * 64 + d) * 2048 + s;
                        o0[off] = h2s((f16)val);
                    }
                }
            }
        }
    }
}

__global__ __launch_bounds__(256) void qk_proj_kernel(
    const float* __restrict__ q, const float* __restrict__ k,
    const float* __restrict__ Wq, const float* __restrict__ Wk,
    const float* __restrict__ bq, const float* __restrict__ bk,
    short* __restrict__ Qh, short* __restrict__ Ql,
    short* __restrict__ Kh, short* __restrict__ Kl) {
    if (blockIdx.z == 0)
        gemm_body<0, 1, 1>(q, Wq, bq, Qh, Ql, nullptr);
    else
        gemm_body<0, 1, 1>(k, Wk, bk, Kh, Kl, nullptr);
}

__global__ __launch_bounds__(256) void v_proj_kernel(const float* __restrict__ v,
                                                     const float* __restrict__ Wv,
                                                     const float* __restrict__ bv,
                                                     short* __restrict__ Vt_g) {
    gemm_body<0, 0, 3>(v, Wv, bv, Vt_g, nullptr, nullptr);
}

__global__ __launch_bounds__(256) void oproj_kernel2(const short* __restrict__ Xb,
                                                     const float* __restrict__ Wo,
                                                     const float* __restrict__ bo,
                                                     float* __restrict__ out) {
    gemm_body<1, 0, 0>(Xb, Wo, bo, nullptr, nullptr, out);
}

// Flash attention with threshold mask.
// Q/K hi+lo fp16 [B*H][S][64]; V fp16 TRANSPOSED [B*H][64][S].
// 4 waves/block, 16 q-rows per wave (QBLK=64). Grid (32, 32).
__global__ __launch_bounds__(256, 4) void attn_kernel(const short* __restrict__ Qh,
                                                      const short* __restrict__ Ql,
                                                      const short* __restrict__ Kh,
                                                      const short* __restrict__ Kl,
                                                      const short* __restrict__ Vg,
                                                      const float* __restrict__ rawthr,
                                                      short* __restrict__ Xb) {
    __shared__ __align__(16) short Ksh[64][72];
    __shared__ __align__(16) short Ksl[64][72];
    __shared__ __align__(16) short Vt[64][72];     // [feat][key]
    __shared__ __align__(16) short Ps[4][16][72];  // per-wave P tile
    const int tid = threadIdx.x, lane = tid & 63, w = tid >> 6;
    const int lr = lane & 15, lg = lane >> 4;
    const int bh = blockIdx.y;
    const int b = bh >> 4, h = bh & 15;
    const size_t base = (size_t)bh * 2048 * 64;  // also == bh*64*2048 for V
    const float rt = rawthr[h];
    const float thr = rt > 20.f ? rt : log1pf(expf(rt));
    const int qrow = blockIdx.x * 64 + w * 16;

    // Q fragments (hi+lo) in registers: rows qrow..qrow+15, feats 0..63
    h8 qfh[2], qfl[2];
#pragma unroll
    for (int kk = 0; kk < 2; ++kk) {
        const size_t off = base + (size_t)(qrow + lr) * 64 + kk * 32 + lg * 8;
        qfh[kk] = *(const h8*)(Qh + off);
        qfl[kk] = *(const h8*)(Ql + off);
    }

    f32x4 acc[4] = {};
    float mrun[4], lrun[4];
#pragma unroll
    for (int r = 0; r < 4; ++r) { mrun[r] = -INFINITY; lrun[r] = 0.f; }

    const int skey = tid >> 2;       // 0..63 (K: key row; V: feat row)
    const int sfe = (tid & 3) * 16;  // 0,16,32,48
    short8 khreg0, khreg1, klreg0, klreg1, vreg0, vreg1;
    {
        const size_t offk = base + (size_t)skey * 64 + sfe;
        khreg0 = *(const short8*)(Kh + offk);
        khreg1 = *(const short8*)(Kh + offk + 8);
        klreg0 = *(const short8*)(Kl + offk);
        klreg1 = *(const short8*)(Kl + offk + 8);
        const size_t offv = base + (size_t)skey * 2048 + sfe;
        vreg0 = *(const short8*)(Vg + offv);
        vreg1 = *(const short8*)(Vg + offv + 8);
    }

    for (int kt = 0; kt < 32; ++kt) {
        __syncthreads();  // previous iteration's LDS reads done
        *(short8*)&Ksh[skey][sfe] = khreg0;
        *(short8*)&Ksh[skey][sfe + 8] = khreg1;
        *(short8*)&Ksl[skey][sfe] = klreg0;
        *(short8*)&Ksl[skey][sfe + 8] = klreg1;
        *(short8*)&Vt[skey][sfe] = vreg0;
        *(short8*)&Vt[skey][sfe + 8] = vreg1;
        __syncthreads();
        if (kt + 1 < 32) {  // prefetch next KV tile into regs (overlaps compute)
            const size_t offk = base + (size_t)((kt + 1) * 64 + skey) * 64 + sfe;
            khreg0 = *(const short8*)(Kh + offk);
            khreg1 = *(const short8*)(Kh + offk + 8);
            klreg0 = *(const short8*)(Kl + offk);
            klreg1 = *(const short8*)(Kl + offk + 8);
            const size_t offv = base + (size_t)skey * 2048 + (kt + 1) * 64 + sfe;
            vreg0 = *(const short8*)(Vg + offv);
            vreg1 = *(const short8*)(Vg + offv + 8);
        }
        // S = Q K^T  (3-term split: accurate to ~1e-5)
        f32x4 sc[4] = {};
        __builtin_amdgcn_s_setprio(1);
#pragma unroll
        for (int fn = 0; fn < 4; ++fn) {
#pragma unroll
            for (int kk = 0; kk < 2; ++kk) {
                const h8 khf = *(const h8*)&Ksh[fn * 16 + lr][kk * 32 + lg * 8];
                const h8 klf = *(const h8*)&Ksl[fn * 16 + lr][kk * 32 + lg * 8];
                sc[fn] = __builtin_amdgcn_mfma_f32_16x16x32_f16(qfh[kk], khf, sc[fn], 0, 0, 0);
                sc[fn] = __builtin_amdgcn_mfma_f32_16x16x32_f16(qfl[kk], khf, sc[fn], 0, 0, 0);
                sc[fn] = __builtin_amdgcn_mfma_f32_16x16x32_f16(qfh[kk], klf, sc[fn], 0, 0, 0);
            }
        }
        __builtin_amdgcn_s_setprio(0);
        // scale, threshold-mask, online softmax. C-frag row = lg*4+i (0..15)
        float corr[4];
#pragma unroll
        for (int i = 0; i < 4; ++i) {
            float mx = -INFINITY;
#pragma unroll
            for (int fn = 0; fn < 4; ++fn) {
                float s = sc[fn][i] * 0.125f;
                s = (s <= thr) ? -1e9f : s;
                sc[fn][i] = s;
                mx = fmaxf(mx, s);
            }
            mx = fmaxf(mx, __shfl_xor(mx, 1));
            mx = fmaxf(mx, __shfl_xor(mx, 2));
            mx = fmaxf(mx, __shfl_xor(mx, 4));
            mx = fmaxf(mx, __shfl_xor(mx, 8));
            const float mnew = fmaxf(mrun[i], mx);
            const float c = __expf(mrun[i] - mnew);  // exp(-inf)=0 on first tile
            float sum = 0.f;
#pragma unroll
            for (int fn = 0; fn < 4; ++fn) {
                const float p = __expf(sc[fn][i] - mnew);
                sc[fn][i] = p;
                sum += p;
            }
            sum += __shfl_xor(sum, 1);
            sum += __shfl_xor(sum, 2);
            sum += __shfl_xor(sum, 4);
            sum += __shfl_xor(sum, 8);
            lrun[i] = lrun[i] * c + sum;
            mrun[i] = mnew;
            corr[i] = c;
        }
#pragma unroll
        for (int fv = 0; fv < 4; ++fv)
#pragma unroll
            for (int i = 0; i < 4; ++i) acc[fv][i] *= corr[i];
        // P -> LDS (C-layout -> A-layout relayout), per-wave buffer, no barrier needed
#pragma unroll
        for (int fn = 0; fn < 4; ++fn)
#pragma unroll
            for (int i = 0; i < 4; ++i)
                Ps[w][lg * 4 + i][fn * 16 + lr] = h2s((f16)sc[fn][i]);
        // O += P V
        h8 pa[2];
#pragma unroll
        for (int kk = 0; kk < 2; ++kk)
            pa[kk] = *(const h8*)&Ps[w][lr][kk * 32 + lg * 8];
        __builtin_amdgcn_s_setprio(1);
#pragma unroll
        for (int kk = 0; kk < 2; ++kk) {
#pragma unroll
            for (int fv = 0; fv < 4; ++fv) {
                const h8 vf = *(const h8*)&Vt[fv * 16 + lr][kk * 32 + lg * 8];
                acc[fv] = __builtin_amdgcn_mfma_f32_16x16x32_f16(pa[kk], vf, acc[fv], 0, 0, 0);
            }
        }
        __builtin_amdgcn_s_setprio(0);
    }
    // epilogue: x = acc / l, store fp16 to [B,S,H*64]
#pragma unroll
    for (int i = 0; i < 4; ++i) {
        const float inv = 1.f / lrun[i];
        const int s = qrow + lg * 4 + i;
#pragma unroll
        for (int fv = 0; fv < 4; ++fv) {
            const int d = fv * 16 + lr;
            Xb[((size_t)(b * 2048 + s) << 10) + (h << 6) + d] = h2s((f16)(acc[fv][i] * inv));
        }
    }
}

extern "C" void kernel_launch(void* const* d_in, const int* in_sizes, int n_in,
                              void* d_out, int out_size, void* d_ws, size_t ws_size,
                              hipStream_t stream) {
    const float* q = (const float*)d_in[0];
    const float* k = (const float*)d_in[1];
    const float* v = (const float*)d_in[2];
    const float* Wq = (const float*)d_in[3];
    const float* bq = (const float*)d_in[4];
    const float* Wk = (const float*)d_in[5];
    const float* bk = (const float*)d_in[6];
    const float* Wv = (const float*)d_in[7];
    const float* bv = (const float*)d_in[8];
    const float* Wo = (const float*)d_in[9];
    const float* bo = (const float*)d_in[10];
    const float* thr = (const float*)d_in[11];
    float* out = (float*)d_out;

    const size_t HS = (size_t)2 * 16 * 2048 * 64;  // 4,194,304 elems per tensor
    short* Qh = (short*)d_ws;
    short* Ql = Qh + HS;
    short* Kh = Ql + HS;
    short* Kl = Kh + HS;
    short* Vb = Kl + HS;  // transposed [B,H,64,S]
    short* Xb = Vb + HS;

    qk_proj_kernel<<<dim3(32, 8, 2), 256, 0, stream>>>(q, k, Wq, Wk, bq, bk, Qh, Ql, Kh, Kl);
    v_proj_kernel<<<dim3(32, 8), 256, 0, stream>>>(v, Wv, bv, Vb);
    attn_kernel<<<dim3(32, 32), 256, 0, stream>>>(Qh, Ql, Kh, Kl, Vb, thr, Xb);
    oproj_kernel2<<<dim3(32, 8), 256, 0, stream>>>(Xb, Wo, bo, out);
}

// Round 4
// 204.461 us; speedup vs baseline: 1.4550x; 1.2443x over previous
//
#include <hip/hip_runtime.h>
#include <hip/hip_bf16.h>

typedef _Float16 f16;
typedef __attribute__((ext_vector_type(8))) f16 h8;
typedef __attribute__((ext_vector_type(4))) float f32x4;
typedef __attribute__((ext_vector_type(8))) short short8;
typedef __attribute__((ext_vector_type(4))) short short4_t;

static __device__ __forceinline__ short h2s(f16 h) { return __builtin_bit_cast(short, h); }

#define BM 128
#define BKD 32
#define LDK 40  // 32 + 8 shorts pad; row stride 80 B

// C = A[M][K] @ W[N][K]^T + bias.
// AMODE: 0 = A fp32 global, 1 = A fp16 (short) global.
// SPLIT: 1 = hi/lo split staging of A and B, 3-term MFMA (fp32-accurate).
// EPI:   0 = fp32 out [M][1024]; 1 = fp16 hi/lo to o0/o1 [B,H,S,64];
//        2 = fp16 to o0 [B,H,S,64]; 3 = fp16 to o0 TRANSPOSED [B,H,64,S].
template <int AMODE, int SPLIT, int EPI>
static __device__ __forceinline__ void gemm_body(const void* __restrict__ Av,
                                                 const float* __restrict__ W,
                                                 const float* __restrict__ bias,
                                                 short* __restrict__ o0,
                                                 short* __restrict__ o1,
                                                 float* __restrict__ of) {
    __shared__ __align__(16) short smem[(SPLIT ? 4 : 2) * BM * LDK];
    short* Ah = smem;
    short* Al = smem + BM * LDK;                    // used only if SPLIT
    short* Bh = smem + (SPLIT ? 2 : 1) * BM * LDK;
    short* Bl = smem + 3 * BM * LDK;                // used only if SPLIT

    const int K = 1024;
    const int tid = threadIdx.x;
    const int lane = tid & 63;
    const int w = tid >> 6;
    const int lr = lane & 15, lg = lane >> 4;
    const int wm = (w & 1) * 64, wn = (w >> 1) * 64;
    const int m0 = blockIdx.x * BM, n0 = blockIdx.y * BM;

    const int sr = tid >> 1;        // staged row 0..127
    const int sc = (tid & 1) * 16;  // staged col 0 or 16

    f32x4 acc[4][4] = {};

    float a_f[16];
    float b_f[16];
    short8 a_h8[2];

    // prologue: load tile t=0 into regs
    {
        const float* Bp = W + (size_t)(n0 + sr) * K + sc;
#pragma unroll
        for (int i = 0; i < 4; i++) {
            float4 t = *(const float4*)(Bp + 4 * i);
            b_f[4 * i] = t.x; b_f[4 * i + 1] = t.y; b_f[4 * i + 2] = t.z; b_f[4 * i + 3] = t.w;
        }
        if (AMODE == 1) {
            const short* Ap = (const short*)Av + (size_t)(m0 + sr) * K + sc;
            a_h8[0] = *(const short8*)(Ap);
            a_h8[1] = *(const short8*)(Ap + 8);
        } else {
            const float* Ap = (const float*)Av + (size_t)(m0 + sr) * K + sc;
#pragma unroll
            for (int i = 0; i < 4; i++) {
                float4 t = *(const float4*)(Ap + 4 * i);
                a_f[4 * i] = t.x; a_f[4 * i + 1] = t.y; a_f[4 * i + 2] = t.z; a_f[4 * i + 3] = t.w;
            }
        }
    }

    const int NT = K / BKD;  // 32
    for (int t = 0; t < NT; ++t) {
        // stage current regs -> LDS (convert fp32 -> fp16 hi[/lo])
        {
            short8 bh0, bh1, bl0, bl1;
#pragma unroll
            for (int j = 0; j < 8; ++j) {
                f16 h0 = (f16)b_f[j];
                f16 h1 = (f16)b_f[8 + j];
                bh0[j] = h2s(h0);
                bh1[j] = h2s(h1);
                if (SPLIT) {
                    bl0[j] = h2s((f16)(b_f[j] - (float)h0));
                    bl1[j] = h2s((f16)(b_f[8 + j] - (float)h1));
                }
            }
            *(short8*)&Bh[sr * LDK + sc] = bh0;
            *(short8*)&Bh[sr * LDK + sc + 8] = bh1;
            if (SPLIT) {
                *(short8*)&Bl[sr * LDK + sc] = bl0;
                *(short8*)&Bl[sr * LDK + sc + 8] = bl1;
            }
            if (AMODE == 1) {
                *(short8*)&Ah[sr * LDK + sc] = a_h8[0];
                *(short8*)&Ah[sr * LDK + sc + 8] = a_h8[1];
            } else {
                short8 ah0, ah1, al0, al1;
#pragma unroll
                for (int j = 0; j < 8; ++j) {
                    f16 h0 = (f16)a_f[j];
                    f16 h1 = (f16)a_f[8 + j];
                    ah0[j] = h2s(h0);
                    ah1[j] = h2s(h1);
                    if (SPLIT) {
                        al0[j] = h2s((f16)(a_f[j] - (float)h0));
                        al1[j] = h2s((f16)(a_f[8 + j] - (float)h1));
                    }
                }
                *(short8*)&Ah[sr * LDK + sc] = ah0;
                *(short8*)&Ah[sr * LDK + sc + 8] = ah1;
                if (SPLIT) {
                    *(short8*)&Al[sr * LDK + sc] = al0;
                    *(short8*)&Al[sr * LDK + sc + 8] = al1;
                }
            }
        }
        __syncthreads();
        // prefetch next tile into regs
        if (t + 1 < NT) {
            const int ko = (t + 1) * BKD;
            const float* Bp = W + (size_t)(n0 + sr) * K + ko + sc;
#pragma unroll
            for (int i = 0; i < 4; i++) {
                float4 tv = *(const float4*)(Bp + 4 * i);
                b_f[4 * i] = tv.x; b_f[4 * i + 1] = tv.y; b_f[4 * i + 2] = tv.z; b_f[4 * i + 3] = tv.w;
            }
            if (AMODE == 1) {
                const short* Ap = (const short*)Av + (size_t)(m0 + sr) * K + ko + sc;
                a_h8[0] = *(const short8*)(Ap);
                a_h8[1] = *(const short8*)(Ap + 8);
            } else {
                const float* Ap = (const float*)Av + (size_t)(m0 + sr) * K + ko + sc;
#pragma unroll
                for (int i = 0; i < 4; i++) {
                    float4 tv = *(const float4*)(Ap + 4 * i);
                    a_f[4 * i] = tv.x; a_f[4 * i + 1] = tv.y; a_f[4 * i + 2] = tv.z; a_f[4 * i + 3] = tv.w;
                }
            }
        }
        // compute current tile from LDS
        {
            h8 afh[4], bfh[4], afl[4], bfl[4];
#pragma unroll
            for (int f = 0; f < 4; ++f) {
                afh[f] = *(const h8*)&Ah[(wm + f * 16 + lr) * LDK + lg * 8];
                bfh[f] = *(const h8*)&Bh[(wn + f * 16 + lr) * LDK + lg * 8];
                if (SPLIT) {
                    afl[f] = *(const h8*)&Al[(wm + f * 16 + lr) * LDK + lg * 8];
                    bfl[f] = *(const h8*)&Bl[(wn + f * 16 + lr) * LDK + lg * 8];
                }
            }
#pragma unroll
            for (int i = 0; i < 4; i++)
#pragma unroll
                for (int j = 0; j < 4; j++) {
                    acc[i][j] = __builtin_amdgcn_mfma_f32_16x16x32_f16(afh[i], bfh[j], acc[i][j], 0, 0, 0);
                    if (SPLIT) {
                        acc[i][j] = __builtin_amdgcn_mfma_f32_16x16x32_f16(afl[i], bfh[j], acc[i][j], 0, 0, 0);
                        acc[i][j] = __builtin_amdgcn_mfma_f32_16x16x32_f16(afh[i], bfl[j], acc[i][j], 0, 0, 0);
                    }
                }
        }
        __syncthreads();
    }

    // epilogue. C-frag: row=(lane>>4)*4+i, col=lane&15
#pragma unroll
    for (int fn = 0; fn < 4; ++fn) {
        const int n = n0 + wn + fn * 16 + lr;
        const float bia = bias[n];
#pragma unroll
        for (int fm = 0; fm < 4; ++fm) {
#pragma unroll
            for (int i = 0; i < 4; i++) {
                const int m = m0 + wm + fm * 16 + lg * 4 + i;
                const float val = acc[fm][fn][i] + bia;
                if (EPI == 0) {
                    of[(size_t)m * 1024 + n] = val;
                } else {
                    const int bb = m >> 11, s = m & 2047, hh = n >> 6, d = n & 63;
                    if (EPI == 1) {
                        const size_t off = (((size_t)(bb * 16 + hh) * 2048 + s) << 6) + d;
                        f16 vh = (f16)val;
                        f16 vl = (f16)(val - (float)vh);
                        o0[off] = h2s(vh);
                        o1[off] = h2s(vl);
                    } else if (EPI == 2) {
                        const size_t off = (((size_t)(bb * 16 + hh) * 2048 + s) << 6) + d;
                        o0[off] = h2s((f16)val);
                    } else {  // EPI == 3: transposed [B,H,64,S]
                        const size_t off = ((size_t)(bb * 16 + hh) * 64 + d) * 2048 + s;
                        o0[off] = h2s((f16)val);
                    }
                }
            }
        }
    }
}

__global__ __launch_bounds__(256) void qk_proj_kernel(
    const float* __restrict__ q, const float* __restrict__ k,
    const float* __restrict__ Wq, const float* __restrict__ Wk,
    const float* __restrict__ bq, const float* __restrict__ bk,
    short* __restrict__ Qh, short* __restrict__ Ql,
    short* __restrict__ Kh) {
    if (blockIdx.z == 0)
        gemm_body<0, 1, 1>(q, Wq, bq, Qh, Ql, nullptr);
    else
        gemm_body<0, 1, 2>(k, Wk, bk, Kh, nullptr, nullptr);  // K accurate, rounded once to fp16
}

__global__ __launch_bounds__(256) void v_proj_kernel(const float* __restrict__ v,
                                                     const float* __restrict__ Wv,
                                                     const float* __restrict__ bv,
                                                     short* __restrict__ Vt_g) {
    gemm_body<0, 0, 3>(v, Wv, bv, Vt_g, nullptr, nullptr);
}

__global__ __launch_bounds__(256) void oproj_kernel2(const short* __restrict__ Xb,
                                                     const float* __restrict__ Wo,
                                                     const float* __restrict__ bo,
                                                     float* __restrict__ out) {
    gemm_body<1, 0, 0>(Xb, Wo, bo, nullptr, nullptr, out);
}

// Flash attention with threshold mask, swapped-QK^T layout.
// Q hi+lo fp16 [B*H][S][64]; K fp16 [B*H][S][64]; V fp16 TRANSPOSED [B*H][64][S].
// 4 waves/block, 16 q-rows per wave (QBLK=64). Grid (32, 32).
// Swapped QK^T: S^T = mfma(A=K, B=Q) -> lane lr owns q-row (qrow+lr),
// holding 16 keys in-register (key = fn*16 + lg*4 + i).
#define PSK 76  // Ps row stride in shorts: 38 dwords -> conflict-free b64 writes & b128 reads
__global__ __launch_bounds__(256, 5) void attn_kernel(const short* __restrict__ Qh,
                                                      const short* __restrict__ Ql,
                                                      const short* __restrict__ Kh,
                                                      const short* __restrict__ Vg,
                                                      const float* __restrict__ rawthr,
                                                      short* __restrict__ Xb) {
    __shared__ __align__(16) short Ksh[64][72];
    __shared__ __align__(16) short Vt[64][72];      // [feat][key]
    __shared__ __align__(16) short Ps[4][16][PSK];  // per-wave P tile [q][key]
    const int tid = threadIdx.x, lane = tid & 63, w = tid >> 6;
    const int lr = lane & 15, lg = lane >> 4;
    const int bh = blockIdx.y;
    const int b = bh >> 4, h = bh & 15;
    const size_t base = (size_t)bh * 2048 * 64;  // also == bh*64*2048 for V
    const float rt = rawthr[h];
    const float thr = rt > 20.f ? rt : log1pf(expf(rt));
    const int qrow = blockIdx.x * 64 + w * 16;

    // Q fragments (hi+lo) in registers: rows qrow..qrow+15, feats 0..63
    h8 qfh[2], qfl[2];
#pragma unroll
    for (int kk = 0; kk < 2; ++kk) {
        const size_t off = base + (size_t)(qrow + lr) * 64 + kk * 32 + lg * 8;
        qfh[kk] = *(const h8*)(Qh + off);
        qfl[kk] = *(const h8*)(Ql + off);
    }

    f32x4 acc[4] = {};
    float mrun = -INFINITY, lrun = 0.f;  // per-lane: q-row = qrow + lr

    const int skey = tid >> 2;       // 0..63 (K: key row; V: feat row)
    const int sfe = (tid & 3) * 16;  // 0,16,32,48
    short8 khreg0, khreg1, vreg0, vreg1;
    {
        const size_t offk = base + (size_t)skey * 64 + sfe;
        khreg0 = *(const short8*)(Kh + offk);
        khreg1 = *(const short8*)(Kh + offk + 8);
        const size_t offv = base + (size_t)skey * 2048 + sfe;
        vreg0 = *(const short8*)(Vg + offv);
        vreg1 = *(const short8*)(Vg + offv + 8);
    }

    for (int kt = 0; kt < 32; ++kt) {
        __syncthreads();  // previous iteration's LDS reads done
        *(short8*)&Ksh[skey][sfe] = khreg0;
        *(short8*)&Ksh[skey][sfe + 8] = khreg1;
        *(short8*)&Vt[skey][sfe] = vreg0;
        *(short8*)&Vt[skey][sfe + 8] = vreg1;
        __syncthreads();
        if (kt + 1 < 32) {  // prefetch next KV tile into regs (overlaps compute)
            const size_t offk = base + (size_t)((kt + 1) * 64 + skey) * 64 + sfe;
            khreg0 = *(const short8*)(Kh + offk);
            khreg1 = *(const short8*)(Kh + offk + 8);
            const size_t offv = base + (size_t)skey * 2048 + (kt + 1) * 64 + sfe;
            vreg0 = *(const short8*)(Vg + offv);
            vreg1 = *(const short8*)(Vg + offv + 8);
        }
        // S^T = K Q^T (2-term: exact Q, fp16 K)
        f32x4 sc[4] = {};
        __builtin_amdgcn_s_setprio(1);
#pragma unroll
        for (int fn = 0; fn < 4; ++fn) {
#pragma unroll
            for (int kk = 0; kk < 2; ++kk) {
                const h8 khf = *(const h8*)&Ksh[fn * 16 + lr][kk * 32 + lg * 8];
                sc[fn] = __builtin_amdgcn_mfma_f32_16x16x32_f16(khf, qfh[kk], sc[fn], 0, 0, 0);
                sc[fn] = __builtin_amdgcn_mfma_f32_16x16x32_f16(khf, qfl[kk], sc[fn], 0, 0, 0);
            }
        }
        __builtin_amdgcn_s_setprio(0);
        // scale + threshold-mask; all 16 keys of this lane's q-row are in-register
        float mx = -INFINITY;
#pragma unroll
        for (int fn = 0; fn < 4; ++fn)
#pragma unroll
            for (int i = 0; i < 4; ++i) {
                float s = sc[fn][i] * 0.125f;
                s = (s <= thr) ? -1e9f : s;
                sc[fn][i] = s;
                mx = fmaxf(mx, s);
            }
        // cross-lg reduce (4 replicas of each q-row)
        mx = fmaxf(mx, __shfl_xor(mx, 16));
        mx = fmaxf(mx, __shfl_xor(mx, 32));
        const float mnew = fmaxf(mrun, mx);
        const float corr = __expf(mrun - mnew);  // exp(-inf)=0 on first tile
        float sum = 0.f;
#pragma unroll
        for (int fn = 0; fn < 4; ++fn)
#pragma unroll
            for (int i = 0; i < 4; ++i) {
                const float p = __expf(sc[fn][i] - mnew);
                sc[fn][i] = p;
                sum += p;
            }
        sum += __shfl_xor(sum, 16);
        sum += __shfl_xor(sum, 32);
        lrun = lrun * corr + sum;
        mrun = mnew;
        // P -> LDS: lane lr owns q-row lr, keys fn*16+lg*4..+3 contiguous -> b64 writes
#pragma unroll
        for (int fn = 0; fn < 4; ++fn) {
            short4_t pk;
#pragma unroll
            for (int i = 0; i < 4; ++i) pk[i] = h2s((f16)sc[fn][i]);
            *(short4_t*)&Ps[w][lr][fn * 16 + lg * 4] = pk;
        }
        // rescale acc: acc rows are q = lg*4+i; fetch that row's corr
        float corr_q[4];
#pragma unroll
        for (int i = 0; i < 4; ++i) corr_q[i] = __shfl(corr, lg * 4 + i);
#pragma unroll
        for (int fv = 0; fv < 4; ++fv)
#pragma unroll
            for (int i = 0; i < 4; ++i) acc[fv][i] *= corr_q[i];
        // O += P V
        h8 pa[2];
#pragma unroll
        for (int kk = 0; kk < 2; ++kk)
            pa[kk] = *(const h8*)&Ps[w][lr][kk * 32 + lg * 8];
        __builtin_amdgcn_s_setprio(1);
#pragma unroll
        for (int kk = 0; kk < 2; ++kk) {
#pragma unroll
            for (int fv = 0; fv < 4; ++fv) {
                const h8 vf = *(const h8*)&Vt[fv * 16 + lr][kk * 32 + lg * 8];
                acc[fv] = __builtin_amdgcn_mfma_f32_16x16x32_f16(pa[kk], vf, acc[fv], 0, 0, 0);
            }
        }
        __builtin_amdgcn_s_setprio(0);
    }
    // epilogue: x = acc / l, store fp16 to [B,S,H*64]. acc row q = lg*4+i, col d = fv*16+lr
#pragma unroll
    for (int i = 0; i < 4; ++i) {
        const float lq = __shfl(lrun, lg * 4 + i);
        const float inv = 1.f / lq;
        const int s = qrow + lg * 4 + i;
#pragma unroll
        for (int fv = 0; fv < 4; ++fv) {
            const int d = fv * 16 + lr;
            Xb[((size_t)(b * 2048 + s) << 10) + (h << 6) + d] = h2s((f16)(acc[fv][i] * inv));
        }
    }
}

extern "C" void kernel_launch(void* const* d_in, const int* in_sizes, int n_in,
                              void* d_out, int out_size, void* d_ws, size_t ws_size,
                              hipStream_t stream) {
    const float* q = (const float*)d_in[0];
    const float* k = (const float*)d_in[1];
    const float* v = (const float*)d_in[2];
    const float* Wq = (const float*)d_in[3];
    const float* bq = (const float*)d_in[4];
    const float* Wk = (const float*)d_in[5];
    const float* bk = (const float*)d_in[6];
    const float* Wv = (const float*)d_in[7];
    const float* bv = (const float*)d_in[8];
    const float* Wo = (const float*)d_in[9];
    const float* bo = (const float*)d_in[10];
    const float* thr = (const float*)d_in[11];
    float* out = (float*)d_out;

    const size_t HS = (size_t)2 * 16 * 2048 * 64;  // 4,194,304 elems per tensor
    short* Qh = (short*)d_ws;
    short* Ql = Qh + HS;
    short* Kh = Ql + HS;
    short* Vb = Kh + HS;  // transposed [B,H,64,S]
    short* Xb = Vb + HS;

    qk_proj_kernel<<<dim3(32, 8, 2), 256, 0, stream>>>(q, k, Wq, Wk, bq, bk, Qh, Ql, Kh);
    v_proj_kernel<<<dim3(32, 8), 256, 0, stream>>>(v, Wv, bv, Vb);
    attn_kernel<<<dim3(32, 32), 256, 0, stream>>>(Qh, Ql, Kh, Vb, thr, Xb);
    oproj_kernel2<<<dim3(32, 8), 256, 0, stream>>>(Xb, Wo, bo, out);
}